// Round 6
// baseline (644.370 us; speedup 1.0000x reference)
//
#include <hip/hip_runtime.h>
#include <math.h>

#define NP 11

__device__ __constant__ int g_l1[NP]   = {0,1,2,0,1,1,2,0,1,2,2};
__device__ __constant__ int g_l2[NP]   = {0,1,2,1,0,2,1,2,1,0,2};
__device__ __constant__ int g_l3[NP]   = {0,0,0,1,1,1,1,2,2,2,2};
__device__ __constant__ int g_coff[NP] = {0,1,10,35,44,53,98,143,168,213,238};

typedef _Float16 half8 __attribute__((ext_vector_type(8)));
typedef _Float16 h2 __attribute__((ext_vector_type(2)));
typedef float f32x4 __attribute__((ext_vector_type(4)));

// ---------------- helpers ----------------
__device__ __forceinline__ float bfu(unsigned int v){ return __uint_as_float(v<<16); }
__device__ __forceinline__ unsigned int rne16(float f){
  unsigned int ui=__float_as_uint(f);
  return (ui+0x7fffu+((ui>>16)&1u))>>16;
}
__device__ __forceinline__ unsigned short h16(float f){
  _Float16 h=(_Float16)f;
  return __builtin_bit_cast(unsigned short,h);
}

// ---------------- Wigner-3j pieces (exact replica of reference, fp64) ----------------
__device__ double dfact(int n){ double r=1.0; for(int i=2;i<=n;++i) r*=(double)i; return r; }

__device__ double su2_cg(int j1,int m1,int j2,int m2,int j3,int m3){
  if(m1+m2!=m3) return 0.0;
  int vmin=-j1+j2+m3; if(-j1+m1>vmin) vmin=-j1+m1; if(vmin<0) vmin=0;
  int vmax=j2+j3+m1; int t=j3-j1+j2; if(t<vmax) vmax=t; t=j3+m3; if(t<vmax) vmax=t;
  double C = sqrt((double)(2*j3+1)*dfact(j3+j1-j2)*dfact(j3-j1+j2)*dfact(j1+j2-j3)
      *dfact(j3+m3)*dfact(j3-m3)
      /(dfact(j1+j2+j3+1)*dfact(j1-m1)*dfact(j1+m1)*dfact(j2-m2)*dfact(j2+m2)));
  double S=0.0;
  for(int v=vmin;v<=vmax;++v){
    double sg = ((v+j2+m2)&1)? -1.0:1.0;
    S += sg*dfact(j2+j3+m1-v)*dfact(j1-m1+v)
        /(dfact(v)*dfact(j3-j1+j2-v)*dfact(j3+m3-v)*dfact(v+j1-j2-m3));
  }
  return C*S;
}

__device__ void qelem(int l,int r,int c,double &re,double &im){
  int m=r-l; double a=0.0,b=0.0; const double s=0.70710678118654752440;
  if(m<0){ if(c==l-m) a=s; else if(c==l+m) b=-s; }
  else if(m==0){ if(c==l) a=1.0; }
  else { double sg=(m&1)?-1.0:1.0; if(c==l+m) a=sg*s; else if(c==l-m) b=sg*s; }
  if(l==1){ double tt=a; a=b; b=-tt; }
  else if(l==2){ a=-a; b=-b; }
  re=a; im=b;
}

__device__ int probe_f32(const unsigned short* __restrict__ p, int nelem, int* scnt){
  if(threadIdx.x==0) *scnt=0;
  __syncthreads();
  int M = nelem < 4096 ? nelem : 4096;
  int c=0;
  for(int t=threadIdx.x;t<M;t+=blockDim.x){
    unsigned e=((unsigned)p[t]>>7)&0xFFu;
    if(e!=0u && (e<0x70u || e>0x8Eu)) ++c;
  }
  atomicAdd(scnt,c);
  __syncthreads();
  return (*scnt*8 > M) ? 1 : 0;
}

// ---------------- ONE prep kernel (unchanged) ----------------
// wpre[(p*3+tp)*2240 + w*140 + c] = pack_fp16(W[2c][w], W[2c+1][w])   (col c=u*8+vp)
__global__ void prep(const unsigned short* __restrict__ x,
                     const unsigned short* __restrict__ wq,
                     const unsigned short* __restrict__ wk,
                     const unsigned short* __restrict__ wv,
                     const unsigned short* __restrict__ wd,
                     int nx,int nw,int nd,
                     float* __restrict__ c3j, unsigned int* __restrict__ cgh,
                     unsigned int* __restrict__ wpre){
  const int p=blockIdx.x, tp=blockIdx.y;
  __shared__ double cg[125];
  __shared__ double outv[125];
  __shared__ double nrm;
  __shared__ int scnt;

  const unsigned short* ww=(tp==0)?wq:((tp==1)?wk:wv);
  const int f32 = probe_f32(ww,nw,&scnt);

  {
    unsigned int* dst=wpre+(size_t)(p*3+tp)*2240;
    for(int t=threadIdx.x;t<2048;t+=256){
      int w=t>>7, c=t&127;
      int i0=c*32+w, i1=i0+16;
      float f0,f1;
      if(f32){
        const float* wf=(const float*)ww+(size_t)p*4096;
        f0=wf[i0]; f1=wf[i1];
      }else{
        const unsigned short* wsp=ww+(size_t)p*4096;
        f0=bfu(wsp[i0]); f1=bfu(wsp[i1]);
      }
      dst[w*140+c]=(unsigned int)h16(f0)|((unsigned int)h16(f1)<<16);
    }
  }

  if(tp==0){
    int l1=g_l1[p], l2=g_l2[p], l3=g_l3[p];
    int d1=2*l1+1, d2=2*l2+1, d3=2*l3+1;
    int tot=d1*d2*d3;
    for(int t=threadIdx.x;t<tot;t+=256){
      int i=t/(d2*d3), k=(t/d3)%d2, n=t%d3;
      cg[t]=su2_cg(l1,i-l1,l2,k-l2,l3,n-l3);
    }
    __syncthreads();
    for(int t=threadIdx.x;t<tot;t+=256){
      int a=t/(d2*d3), b=(t/d3)%d2, c=t%d3;
      double sre=0.0;
      for(int i=0;i<d1;++i){ double q1r,q1i; qelem(l1,i,a,q1r,q1i);
        for(int k=0;k<d2;++k){ double q2r,q2i; qelem(l2,k,b,q2r,q2i);
          double pr=q1r*q2r-q1i*q2i, pi=q1r*q2i+q1i*q2r;
          for(int n=0;n<d3;++n){ double q3r,q3i; qelem(l3,n,c,q3r,q3i);
            sre += (pr*q3r + pi*q3i) * cg[(i*d2+k)*d3+n];
          }
        }
      }
      outv[t]=sre;
    }
    __syncthreads();
    if(threadIdx.x==0){
      double s=0.0; for(int t=0;t<tot;++t) s+=outv[t]*outv[t];
      nrm=sqrt(s);
    }
    __syncthreads();
    const float scl_[3]={0.03608439182435161f,0.05412658773652741f,0.06987712429686843f};
    float s=scl_[l3];
    for(int t=threadIdx.x;t<tot;t+=256){
      float val=(float)(outv[t]/nrm);
      c3j[g_coff[p]+t]=val;
      unsigned int h=(unsigned int)h16(val*s);
      cgh[g_coff[p]+t]=h|(h<<16);
    }
  }

  if(p==0 && tp==0){
    int xf=probe_f32(x,nx,&scnt);
    if(threadIdx.x==0) c3j[363]=(float)xf;
    int df=probe_f32(wd,nd,&scnt);
    if(threadIdx.x==0) c3j[367]=(float)df;
  }
}

// ---------------- per-path compute: one wave owns 16 nodes ----------------
// D[w=16][node=16] per (tp,k). A-operand = W direct from GLOBAL (L1/L2-resident,
// all waves read the same 27KB triple): row=lane&15=w, K=8*(lane>>4)+e.
// B-operand = node data (col=lane&15=node, K same). K = u*16+v (wpre ordering).
// Lane (nd,qp): u = 2s + (qp>>1), v-half = 8*(qp&1). h2 packs = (v,v+1).
template<int D1,int D2,int D3>
__device__ __forceinline__ void do_path(const unsigned int* __restrict__ xrow,
                                        const unsigned int* __restrict__ wg,
                                        const unsigned int* __restrict__ cgp,
                                        f32x4 (&aq)[D3], f32x4 (&ak)[D3], f32x4 (&av)[D3],
                                        int hsel, int bsel)
{
  constexpr int O1=(D1==1)?0:((D1==3)?8:32);
  constexpr int O2=(D2==1)?0:((D2==3)?8:32);
  constexpr int KC=(4*D1*D3<=48)?D3:(48/(4*D1));
  // cache this lane's x2 (v,v+1)-packs: vp = 4*hsel + e
  h2 x2p[4][D2];
  {
    const int vb=O2+4*hsel*D2;
    #pragma unroll
    for(int e=0;e<4;++e)
      #pragma unroll
      for(int j=0;j<D2;++j)
        x2p[e][j]=__builtin_bit_cast(h2,xrow[vb+e*D2+j]);
  }
  #pragma unroll
  for(int k0=0;k0<D3;k0+=KC){
    // ar[kk][i][e] = sum_j (scale*C)[i,j,k0+kk] * x2pair  (fp16, scale folded in cgh)
    h2 ar[KC][D1][4];
    #pragma unroll
    for(int kk=0;kk<KC;++kk){
      if(k0+kk<D3){
        #pragma unroll
        for(int i=0;i<D1;++i){
          #pragma unroll
          for(int e=0;e<4;++e){
            h2 s={(_Float16)0.f,(_Float16)0.f};
            #pragma unroll
            for(int j=0;j<D2;++j)
              s+=__builtin_bit_cast(h2,cgp[(i*D2+j)*D3+(k0+kk)])*x2p[e][j];
            ar[kk][i][e]=s;
          }
        }
      }
    }
    for(int s=0;s<8;++s){                       // K-steps (runtime loop, code-size)
      uint4 wq4=*(const uint4*)(wg+s*16);
      uint4 wk4=*(const uint4*)(wg+2240+s*16);
      uint4 wv4=*(const uint4*)(wg+4480+s*16);
      // x1[u = 2s+bsel][i] as dup-h2, from the shared pack image
      h2 x1d[D1];
      #pragma unroll
      for(int i=0;i<D1;++i){
        unsigned int X=xrow[O1+s*D1+i];
        unsigned int lo=X&0xffffu, hi=X>>16;
        unsigned int d=bsel?(hi|(hi<<16)):(lo|(lo<<16));
        x1d[i]=__builtin_bit_cast(h2,d);
      }
      #pragma unroll
      for(int kk=0;kk<KC;++kk){
        if(k0+kk<D3){
          h2 b0={(_Float16)0.f,(_Float16)0.f},b1=b0,b2=b0,b3=b0;
          #pragma unroll
          for(int i=0;i<D1;++i){
            b0+=x1d[i]*ar[kk][i][0];
            b1+=x1d[i]*ar[kk][i][1];
            b2+=x1d[i]*ar[kk][i][2];
            b3+=x1d[i]*ar[kk][i][3];
          }
          uint4 bu;
          bu.x=__builtin_bit_cast(unsigned int,b0);
          bu.y=__builtin_bit_cast(unsigned int,b1);
          bu.z=__builtin_bit_cast(unsigned int,b2);
          bu.w=__builtin_bit_cast(unsigned int,b3);
          half8 B=__builtin_bit_cast(half8,bu);
          aq[k0+kk]=__builtin_amdgcn_mfma_f32_16x16x32_f16(__builtin_bit_cast(half8,wq4),B,aq[k0+kk],0,0,0);
          ak[k0+kk]=__builtin_amdgcn_mfma_f32_16x16x32_f16(__builtin_bit_cast(half8,wk4),B,ak[k0+kk],0,0,0);
          av[k0+kk]=__builtin_amdgcn_mfma_f32_16x16x32_f16(__builtin_bit_cast(half8,wv4),B,av[k0+kk],0,0,0);
        }
      }
    }
  }
}

// per-group dot partial: P = sum_{u,v} Wd[u,v] * sum_m q[u,m]*k[v,m]
// lane holds u-rows 4*qp..4*qp+3 for its node; k[v] gathered by shuffle.
template<int D3>
__device__ __forceinline__ float dot_group(const f32x4 (&aq)[D3], const f32x4 (&ak)[D3],
                                           const float* __restrict__ sWd_l,
                                           int nd, int qp)
{
  float P=0.f;
  #pragma unroll
  for(int v=0;v<16;++v){
    float kv[D3];
    const int src=nd+((v>>2)<<4);
    #pragma unroll
    for(int m=0;m<D3;++m) kv[m]=__shfl(ak[m][v&3],src,64);
    #pragma unroll
    for(int r=0;r<4;++r){
      float dm=0.f;
      #pragma unroll
      for(int m=0;m<D3;++m) dm+=aq[m][r]*kv[m];
      P+=sWd_l[(4*qp+r)*16+v]*dm;
    }
  }
  return P;
}

// LDS layout (dwords): [0..9471] raw-x stage / out image (overlay, disjoint in time)
//                      [9472..14399] sXp 64 nodes x 77   [14400..15167] sWd
#define XPOFF 9472
#define WDOFF 14400

__global__ __launch_bounds__(256,2) __attribute__((amdgpu_waves_per_eu(2,2)))
void tfn_main(
    const unsigned short* __restrict__ xin,
    const unsigned int* __restrict__ wpre,
    const unsigned int* __restrict__ cgh,
    const unsigned short* __restrict__ wd,
    const float* __restrict__ c3j,
    unsigned short* __restrict__ outp, int N)
{
  __shared__ __align__(16) unsigned int SM[15168];

  const int tid=threadIdx.x;
  const int lane=tid&63, wave=tid>>6;
  const int nd=lane&15, qp=lane>>4;
  const int hsel=qp&1, bsel=qp>>1;
  const int nl=wave*16+nd;                 // node within block (0..63)
  const int node0=blockIdx.x*64;
  const int nvalid=(N-node0)<64?(N-node0):64;

  const int xf32 = c3j[363]!=0.0f;
  const int df32 = c3j[367]!=0.0f;
  const float c0=c3j[0], c1=c3j[1], c2=c3j[10];

  // ---- stage raw x into LDS (dw 0..), zero-fill invalid nodes ----
  if(!xf32){
    const uint4* xsrc=(const uint4*)(xin+(size_t)node0*144);
    for(int idx=tid;idx<1152;idx+=256){    // 64 nodes * 18 uint4 (bf16)
      int node=idx/18;
      uint4 v={0u,0u,0u,0u};
      if(node<nvalid) v=xsrc[idx];
      ((uint4*)SM)[idx]=v;
    }
  }else{
    const uint4* xsrc=(const uint4*)((const float*)xin+(size_t)node0*144);
    for(int idx=tid;idx<2304;idx+=256){    // 64 nodes * 36 uint4 (f32)
      int node=idx/36;
      uint4 v={0u,0u,0u,0u};
      if(node<nvalid) v=xsrc[idx];
      ((uint4*)SM)[idx]=v;
    }
  }
  // ---- sWd ----
  if(!df32){ for(int t=tid;t<768;t+=256) ((float*)SM)[WDOFF+t]=bfu((unsigned int)wd[t]); }
  else     { const float* wdf=(const float*)wd; for(int t=tid;t<768;t+=256) ((float*)SM)[WDOFF+t]=wdf[t]; }
  __syncthreads();

  // ---- build packed fp16 (v,v+1)-pair image sXp[64][77] ----
  {
    const unsigned short* raw16=(const unsigned short*)SM;
    const float* rawf=(const float*)SM;
    for(int t=tid;t<64*72;t+=256){
      int n=t/72, g=t-n*72;
      int fa,fb;
      if(g<8){ fa=2*g; fb=fa+1; }
      else if(g<32){ int gg=g-8; int vp=gg/3, j=gg-3*vp; fa=16+(2*vp)*3+j; fb=fa+3; }
      else { int gg=g-32; int vp=gg/5, j=gg-5*vp; fa=64+(2*vp)*5+j; fb=fa+5; }
      float va,vb;
      if(!xf32){ va=bfu(raw16[n*144+fa]); vb=bfu(raw16[n*144+fb]); }
      else     { va=rawf[n*144+fa];       vb=rawf[n*144+fb]; }
      SM[XPOFF+n*77+g]=(unsigned int)h16(va)|((unsigned int)h16(vb)<<16);
    }
  }
  __syncthreads();
  // From here on: no barriers until the epilogue — waves are fully independent.
  // (sXp/sWd are read-only; W and cgh are read direct from global.)

  const unsigned int* xrow=SM+XPOFF+nl*77;
  const unsigned int* wglane=wpre+nd*140+qp*4;   // per-lane W base (global)
  const float* sWd=(const float*)(SM+WDOFF);

  const f32x4 z4={0.f,0.f,0.f,0.f};
  f32x4 av0[1]={z4};
  f32x4 av1[3]={z4,z4,z4};
  f32x4 av2[5]={z4,z4,z4,z4,z4};
  float dd=0.f;

  { // l3 = 0 : paths 0,1,2
    f32x4 aq[1]={z4}, ak[1]={z4};
    do_path<1,1,1>(xrow,wglane+(size_t)0*6720 ,cgh+0 ,aq,ak,av0,hsel,bsel);
    do_path<3,3,1>(xrow,wglane+(size_t)1*6720 ,cgh+1 ,aq,ak,av0,hsel,bsel);
    do_path<5,5,1>(xrow,wglane+(size_t)2*6720 ,cgh+10,aq,ak,av0,hsel,bsel);
    dd+=c0*dot_group<1>(aq,ak,sWd,nd,qp);
  }
  { // l3 = 1 : paths 3,4,5,6
    f32x4 aq[3]={z4,z4,z4}, ak[3]={z4,z4,z4};
    do_path<1,3,3>(xrow,wglane+(size_t)3*6720 ,cgh+35,aq,ak,av1,hsel,bsel);
    do_path<3,1,3>(xrow,wglane+(size_t)4*6720 ,cgh+44,aq,ak,av1,hsel,bsel);
    do_path<3,5,3>(xrow,wglane+(size_t)5*6720 ,cgh+53,aq,ak,av1,hsel,bsel);
    do_path<5,3,3>(xrow,wglane+(size_t)6*6720 ,cgh+98,aq,ak,av1,hsel,bsel);
    dd+=c1*dot_group<3>(aq,ak,sWd+256,nd,qp);
  }
  { // l3 = 2 : paths 7,8,9,10
    f32x4 aq[5]={z4,z4,z4,z4,z4}, ak[5]={z4,z4,z4,z4,z4};
    do_path<1,5,5>(xrow,wglane+(size_t)7*6720 ,cgh+143,aq,ak,av2,hsel,bsel);
    do_path<3,3,5>(xrow,wglane+(size_t)8*6720 ,cgh+168,aq,ak,av2,hsel,bsel);
    do_path<5,1,5>(xrow,wglane+(size_t)9*6720 ,cgh+213,aq,ak,av2,hsel,bsel);
    do_path<5,5,5>(xrow,wglane+(size_t)10*6720,cgh+238,aq,ak,av2,hsel,bsel);
    dd+=c2*dot_group<5>(aq,ak,sWd+512,nd,qp);
  }

  // ---- attention scalar (reduce over the node's 4 u-lanes) ----
  dd+=__shfl_xor(dd,16,64);
  dd+=__shfl_xor(dd,32,64);
  float ex=dd*0.03608439182435161f*(1.0f/12.0f);   // *sqrt(1/768) / sqrt(144)
  ex=fminf(fmaxf(ex,-80.f),80.f);
  float e=expf(ex);
  float attn=e/(e+1e-10f);

  // ---- write elu(attn*v) image [64][148] f32 (overlays raw-x stage; all raw-x
  //      reads completed before the post-sXp barrier, so no extra barrier needed) ----
  {
    float* row=(float*)SM+nl*148;
    #pragma unroll
    for(int r=0;r<4;++r){
      float v=attn*av0[0][r];
      row[4*qp+r]=(v>0.f)?v:expm1f(v);
    }
    #pragma unroll
    for(int m=0;m<3;++m)
      #pragma unroll
      for(int r=0;r<4;++r){
        float v=attn*av1[m][r];
        row[16+(4*qp+r)*3+m]=(v>0.f)?v:expm1f(v);
      }
    #pragma unroll
    for(int m=0;m<5;++m)
      #pragma unroll
      for(int r=0;r<4;++r){
        float v=attn*av2[m][r];
        row[64+(4*qp+r)*5+m]=(v>0.f)?v:expm1f(v);
      }
  }
  __syncthreads();

  // ---- coalesced store ----
  const float* img=(const float*)SM;
  if(!xf32){
    unsigned int* ob=(unsigned int*)outp;
    for(int t=tid;t<64*72;t+=256){
      int n=t/72, fp=t-n*72;
      if(n<nvalid){
        float v0=img[n*148+2*fp], v1=img[n*148+2*fp+1];
        ob[(size_t)(node0+n)*72+fp]=rne16(v0)|(rne16(v1)<<16);
      }
    }
  }else{
    float* outf=(float*)outp;
    for(int t=tid;t<64*36;t+=256){
      int n=t/36, c=t-n*36;
      if(n<nvalid){
        uint4 v=*(const uint4*)(img+n*148+c*4);
        *((uint4*)(outf+(size_t)(node0+n)*144)+c)=v;
      }
    }
  }
}

extern "C" void kernel_launch(void* const* d_in, const int* in_sizes, int n_in,
                              void* d_out, int out_size, void* d_ws, size_t ws_size,
                              hipStream_t stream){
  (void)n_in; (void)out_size; (void)ws_size;
  const unsigned short* x =(const unsigned short*)d_in[0];
  const unsigned short* wq=(const unsigned short*)d_in[4];
  const unsigned short* wk=(const unsigned short*)d_in[5];
  const unsigned short* wv=(const unsigned short*)d_in[6];
  const unsigned short* wd=(const unsigned short*)d_in[7];
  float* c3j=(float*)d_ws;                                 // [0..362] w3j, [363..367] flags
  unsigned int* cgh=(unsigned int*)d_ws+1024;              // packed scale*C fp16 pairs (363)
  unsigned int* wpre=(unsigned int*)d_ws+2048;             // 11*3*2240 packed fp16 W^T
  int N=in_sizes[0]/144;
  prep<<<dim3(NP,3),dim3(256),0,stream>>>(x,wq,wk,wv,wd,
      in_sizes[0],in_sizes[4],in_sizes[7],c3j,cgh,wpre);
  int nb=(N+63)/64;
  tfn_main<<<dim3(nb),dim3(256),0,stream>>>(x,wpre,cgh,wd,c3j,(unsigned short*)d_out,N);
}

// Round 7
// 340.661 us; speedup vs baseline: 1.8915x; 1.8915x over previous
//
#include <hip/hip_runtime.h>
#include <math.h>

#define NP 11

__device__ __constant__ int g_l1[NP]   = {0,1,2,0,1,1,2,0,1,2,2};
__device__ __constant__ int g_l2[NP]   = {0,1,2,1,0,2,1,2,1,0,2};
__device__ __constant__ int g_l3[NP]   = {0,0,0,1,1,1,1,2,2,2,2};
__device__ __constant__ int g_coff[NP] = {0,1,10,35,44,53,98,143,168,213,238};

typedef _Float16 half8 __attribute__((ext_vector_type(8)));
typedef _Float16 h2 __attribute__((ext_vector_type(2)));
typedef float f32x4 __attribute__((ext_vector_type(4)));

// ---------------- helpers ----------------
__device__ __forceinline__ float bfu(unsigned int v){ return __uint_as_float(v<<16); }
__device__ __forceinline__ unsigned int rne16(float f){
  unsigned int ui=__float_as_uint(f);
  return (ui+0x7fffu+((ui>>16)&1u))>>16;
}
__device__ __forceinline__ unsigned short h16(float f){
  _Float16 h=(_Float16)f;
  return __builtin_bit_cast(unsigned short,h);
}

// ---------------- Wigner-3j pieces (exact replica of reference, fp64) ----------------
__device__ double dfact(int n){ double r=1.0; for(int i=2;i<=n;++i) r*=(double)i; return r; }

__device__ double su2_cg(int j1,int m1,int j2,int m2,int j3,int m3){
  if(m1+m2!=m3) return 0.0;
  int vmin=-j1+j2+m3; if(-j1+m1>vmin) vmin=-j1+m1; if(vmin<0) vmin=0;
  int vmax=j2+j3+m1; int t=j3-j1+j2; if(t<vmax) vmax=t; t=j3+m3; if(t<vmax) vmax=t;
  double C = sqrt((double)(2*j3+1)*dfact(j3+j1-j2)*dfact(j3-j1+j2)*dfact(j1+j2-j3)
      *dfact(j3+m3)*dfact(j3-m3)
      /(dfact(j1+j2+j3+1)*dfact(j1-m1)*dfact(j1+m1)*dfact(j2-m2)*dfact(j2+m2)));
  double S=0.0;
  for(int v=vmin;v<=vmax;++v){
    double sg = ((v+j2+m2)&1)? -1.0:1.0;
    S += sg*dfact(j2+j3+m1-v)*dfact(j1-m1+v)
        /(dfact(v)*dfact(j3-j1+j2-v)*dfact(j3+m3-v)*dfact(v+j1-j2-m3));
  }
  return C*S;
}

__device__ void qelem(int l,int r,int c,double &re,double &im){
  int m=r-l; double a=0.0,b=0.0; const double s=0.70710678118654752440;
  if(m<0){ if(c==l-m) a=s; else if(c==l+m) b=-s; }
  else if(m==0){ if(c==l) a=1.0; }
  else { double sg=(m&1)?-1.0:1.0; if(c==l+m) a=sg*s; else if(c==l-m) b=sg*s; }
  if(l==1){ double tt=a; a=b; b=-tt; }
  else if(l==2){ a=-a; b=-b; }
  re=a; im=b;
}

__device__ int probe_f32(const unsigned short* __restrict__ p, int nelem, int* scnt){
  if(threadIdx.x==0) *scnt=0;
  __syncthreads();
  int M = nelem < 4096 ? nelem : 4096;
  int c=0;
  for(int t=threadIdx.x;t<M;t+=blockDim.x){
    unsigned e=((unsigned)p[t]>>7)&0xFFu;
    if(e!=0u && (e<0x70u || e>0x8Eu)) ++c;
  }
  atomicAdd(scnt,c);
  __syncthreads();
  return (*scnt*8 > M) ? 1 : 0;
}

// ---------------- ONE prep kernel (unchanged) ----------------
// wpre[(p*3+tp)*2240 + w*140 + c] = pack_fp16(W[2c][w], W[2c+1][w])   (col c=u*8+vp)
__global__ void prep(const unsigned short* __restrict__ x,
                     const unsigned short* __restrict__ wq,
                     const unsigned short* __restrict__ wk,
                     const unsigned short* __restrict__ wv,
                     const unsigned short* __restrict__ wd,
                     int nx,int nw,int nd,
                     float* __restrict__ c3j, unsigned int* __restrict__ cgh,
                     unsigned int* __restrict__ wpre){
  const int p=blockIdx.x, tp=blockIdx.y;
  __shared__ double cg[125];
  __shared__ double outv[125];
  __shared__ double nrm;
  __shared__ int scnt;

  const unsigned short* ww=(tp==0)?wq:((tp==1)?wk:wv);
  const int f32 = probe_f32(ww,nw,&scnt);

  {
    unsigned int* dst=wpre+(size_t)(p*3+tp)*2240;
    for(int t=threadIdx.x;t<2048;t+=256){
      int w=t>>7, c=t&127;
      int i0=c*32+w, i1=i0+16;
      float f0,f1;
      if(f32){
        const float* wf=(const float*)ww+(size_t)p*4096;
        f0=wf[i0]; f1=wf[i1];
      }else{
        const unsigned short* wsp=ww+(size_t)p*4096;
        f0=bfu(wsp[i0]); f1=bfu(wsp[i1]);
      }
      dst[w*140+c]=(unsigned int)h16(f0)|((unsigned int)h16(f1)<<16);
    }
  }

  if(tp==0){
    int l1=g_l1[p], l2=g_l2[p], l3=g_l3[p];
    int d1=2*l1+1, d2=2*l2+1, d3=2*l3+1;
    int tot=d1*d2*d3;
    for(int t=threadIdx.x;t<tot;t+=256){
      int i=t/(d2*d3), k=(t/d3)%d2, n=t%d3;
      cg[t]=su2_cg(l1,i-l1,l2,k-l2,l3,n-l3);
    }
    __syncthreads();
    for(int t=threadIdx.x;t<tot;t+=256){
      int a=t/(d2*d3), b=(t/d3)%d2, c=t%d3;
      double sre=0.0;
      for(int i=0;i<d1;++i){ double q1r,q1i; qelem(l1,i,a,q1r,q1i);
        for(int k=0;k<d2;++k){ double q2r,q2i; qelem(l2,k,b,q2r,q2i);
          double pr=q1r*q2r-q1i*q2i, pi=q1r*q2i+q1i*q2r;
          for(int n=0;n<d3;++n){ double q3r,q3i; qelem(l3,n,c,q3r,q3i);
            sre += (pr*q3r + pi*q3i) * cg[(i*d2+k)*d3+n];
          }
        }
      }
      outv[t]=sre;
    }
    __syncthreads();
    if(threadIdx.x==0){
      double s=0.0; for(int t=0;t<tot;++t) s+=outv[t]*outv[t];
      nrm=sqrt(s);
    }
    __syncthreads();
    const float scl_[3]={0.03608439182435161f,0.05412658773652741f,0.06987712429686843f};
    float s=scl_[l3];
    for(int t=threadIdx.x;t<tot;t+=256){
      float val=(float)(outv[t]/nrm);
      c3j[g_coff[p]+t]=val;
      unsigned int h=(unsigned int)h16(val*s);
      cgh[g_coff[p]+t]=h|(h<<16);
    }
  }

  if(p==0 && tp==0){
    int xf=probe_f32(x,nx,&scnt);
    if(threadIdx.x==0) c3j[363]=(float)xf;
    int df=probe_f32(wd,nd,&scnt);
    if(threadIdx.x==0) c3j[367]=(float)df;
  }
}

// ---------------- per-path compute: one wave owns 16 nodes ----------------
// D[w=16][node=16] per (tp,k). A-operand = W direct from GLOBAL (L1-resident:
// 26.9KB triple < 32KB L1, shared by all waves): row=lane&15=w, K=8*(lane>>4)+e.
// B-operand = node data (col=lane&15=node, K same). K = u*16+v (wpre ordering).
// Lane (nd,qp): u = 2s + (qp>>1), v-half = 8*(qp&1). h2 packs = (v,v+1).
// KC=1: k outer (unrolled), ar[D1][4] only; x2 streamed from LDS per (k,e).
template<int D1,int D2,int D3>
__device__ __forceinline__ void do_path(const unsigned int* __restrict__ xrow,
                                        const unsigned int* __restrict__ wg,
                                        const unsigned int* __restrict__ cgp,
                                        f32x4 (&aq)[D3], f32x4 (&ak)[D3], f32x4 (&av)[D3],
                                        int hsel, int bsel)
{
  constexpr int O1=(D1==1)?0:((D1==3)?8:32);
  constexpr int O2=(D2==1)?0:((D2==3)?8:32);
  const h2 z2={(_Float16)0.f,(_Float16)0.f};
  #pragma unroll
  for(int k=0;k<D3;++k){
    // ar[i][e] = sum_j (scale*C)[i,j,k] * x2pair[e][j]   (scale folded in cgh)
    h2 ar[D1][4];
    #pragma unroll
    for(int e=0;e<4;++e){
      h2 x2pj[D2];
      const int vb=O2+(4*hsel+e)*D2;
      #pragma unroll
      for(int j=0;j<D2;++j) x2pj[j]=__builtin_bit_cast(h2,xrow[vb+j]);
      #pragma unroll
      for(int i=0;i<D1;++i){
        h2 s=z2;
        #pragma unroll
        for(int j=0;j<D2;++j)
          s+=__builtin_bit_cast(h2,cgp[(i*D2+j)*D3+k])*x2pj[j];
        ar[i][e]=s;
      }
    }
    for(int s=0;s<8;++s){                       // K-steps (runtime loop, code-size)
      uint4 wq4=*(const uint4*)(wg+s*16);
      uint4 wk4=*(const uint4*)(wg+2240+s*16);
      uint4 wv4=*(const uint4*)(wg+4480+s*16);
      // x1[u = 2s+bsel][i] as dup-h2, from the shared pack image
      h2 b0=z2,b1=z2,b2=z2,b3=z2;
      #pragma unroll
      for(int i=0;i<D1;++i){
        unsigned int X=xrow[O1+s*D1+i];
        unsigned int lo=X&0xffffu, hi=X>>16;
        unsigned int d=bsel?(hi|(hi<<16)):(lo|(lo<<16));
        h2 x1d=__builtin_bit_cast(h2,d);
        b0+=x1d*ar[i][0];
        b1+=x1d*ar[i][1];
        b2+=x1d*ar[i][2];
        b3+=x1d*ar[i][3];
      }
      uint4 bu;
      bu.x=__builtin_bit_cast(unsigned int,b0);
      bu.y=__builtin_bit_cast(unsigned int,b1);
      bu.z=__builtin_bit_cast(unsigned int,b2);
      bu.w=__builtin_bit_cast(unsigned int,b3);
      half8 B=__builtin_bit_cast(half8,bu);
      aq[k]=__builtin_amdgcn_mfma_f32_16x16x32_f16(__builtin_bit_cast(half8,wq4),B,aq[k],0,0,0);
      ak[k]=__builtin_amdgcn_mfma_f32_16x16x32_f16(__builtin_bit_cast(half8,wk4),B,ak[k],0,0,0);
      av[k]=__builtin_amdgcn_mfma_f32_16x16x32_f16(__builtin_bit_cast(half8,wv4),B,av[k],0,0,0);
    }
  }
}

// per-group dot partial: P = sum_{u,v} Wd[u,v] * sum_m q[u,m]*k[v,m]
// lane holds u-rows 4*qp..4*qp+3 for its node; k[v] gathered by shuffle.
template<int D3>
__device__ __forceinline__ float dot_group(const f32x4 (&aq)[D3], const f32x4 (&ak)[D3],
                                           const float* __restrict__ sWd_l,
                                           int nd, int qp)
{
  float P=0.f;
  #pragma unroll
  for(int v=0;v<16;++v){
    float kv[D3];
    const int src=nd+((v>>2)<<4);
    #pragma unroll
    for(int m=0;m<D3;++m) kv[m]=__shfl(ak[m][v&3],src,64);
    #pragma unroll
    for(int r=0;r<4;++r){
      float dm=0.f;
      #pragma unroll
      for(int m=0;m<D3;++m) dm+=aq[m][r]*kv[m];
      P+=sWd_l[(4*qp+r)*16+v]*dm;
    }
  }
  return P;
}

// LDS layout (dwords): [0..9471] raw-x stage / UNSCALED v image [64][148] (overlay)
//                      [9472..14399] sXp 64 nodes x 77   [14400..15167] sWd
//                      [15168..15231] attn per node
#define XPOFF 9472
#define WDOFF 14400
#define ATOFF 15168

__global__ __launch_bounds__(256) __attribute__((amdgpu_waves_per_eu(2,2)))
void tfn_main(
    const unsigned short* __restrict__ xin,
    const unsigned int* __restrict__ wpre,
    const unsigned int* __restrict__ cgh,
    const unsigned short* __restrict__ wd,
    const float* __restrict__ c3j,
    unsigned short* __restrict__ outp, int N)
{
  __shared__ __align__(16) unsigned int SM[15232];

  const int tid=threadIdx.x;
  const int lane=tid&63, wave=tid>>6;
  const int nd=lane&15, qp=lane>>4;
  const int hsel=qp&1, bsel=qp>>1;
  const int nl=wave*16+nd;                 // node within block (0..63)
  const int node0=blockIdx.x*64;
  const int nvalid=(N-node0)<64?(N-node0):64;

  const int xf32 = c3j[363]!=0.0f;
  const int df32 = c3j[367]!=0.0f;
  const float c0=c3j[0], c1=c3j[1], c2=c3j[10];

  // ---- stage raw x into LDS (dw 0..), zero-fill invalid nodes ----
  if(!xf32){
    const uint4* xsrc=(const uint4*)(xin+(size_t)node0*144);
    for(int idx=tid;idx<1152;idx+=256){    // 64 nodes * 18 uint4 (bf16)
      int node=idx/18;
      uint4 v={0u,0u,0u,0u};
      if(node<nvalid) v=xsrc[idx];
      ((uint4*)SM)[idx]=v;
    }
  }else{
    const uint4* xsrc=(const uint4*)((const float*)xin+(size_t)node0*144);
    for(int idx=tid;idx<2304;idx+=256){    // 64 nodes * 36 uint4 (f32)
      int node=idx/36;
      uint4 v={0u,0u,0u,0u};
      if(node<nvalid) v=xsrc[idx];
      ((uint4*)SM)[idx]=v;
    }
  }
  // ---- sWd ----
  if(!df32){ for(int t=tid;t<768;t+=256) ((float*)SM)[WDOFF+t]=bfu((unsigned int)wd[t]); }
  else     { const float* wdf=(const float*)wd; for(int t=tid;t<768;t+=256) ((float*)SM)[WDOFF+t]=wdf[t]; }
  __syncthreads();

  // ---- build packed fp16 (v,v+1)-pair image sXp[64][77] ----
  {
    const unsigned short* raw16=(const unsigned short*)SM;
    const float* rawf=(const float*)SM;
    for(int t=tid;t<64*72;t+=256){
      int n=t/72, g=t-n*72;
      int fa,fb;
      if(g<8){ fa=2*g; fb=fa+1; }
      else if(g<32){ int gg=g-8; int vp=gg/3, j=gg-3*vp; fa=16+(2*vp)*3+j; fb=fa+3; }
      else { int gg=g-32; int vp=gg/5, j=gg-5*vp; fa=64+(2*vp)*5+j; fb=fa+5; }
      float va,vb;
      if(!xf32){ va=bfu(raw16[n*144+fa]); vb=bfu(raw16[n*144+fb]); }
      else     { va=rawf[n*144+fa];       vb=rawf[n*144+fb]; }
      SM[XPOFF+n*77+g]=(unsigned int)h16(va)|((unsigned int)h16(vb)<<16);
    }
  }
  __syncthreads();
  // From here on: no barriers until the epilogue — waves are fully independent.
  // (sXp/sWd are read-only; W and cgh read direct from global; v-accs parked
  //  UNSCALED into the image area [0..9471], disjoint from sXp.)

  const unsigned int* xrow=SM+XPOFF+nl*77;
  const unsigned int* wglane=wpre+nd*140+qp*4;   // per-lane W base (global)
  const float* sWd=(const float*)(SM+WDOFF);
  float* row=(float*)SM+nl*148;

  const f32x4 z4={0.f,0.f,0.f,0.f};
  float dd=0.f;

  { // l3 = 0 : paths 0,1,2
    f32x4 aq[1]={z4}, ak[1]={z4}, av[1]={z4};
    do_path<1,1,1>(xrow,wglane+(size_t)0*6720 ,cgh+0 ,aq,ak,av,hsel,bsel);
    do_path<3,3,1>(xrow,wglane+(size_t)1*6720 ,cgh+1 ,aq,ak,av,hsel,bsel);
    do_path<5,5,1>(xrow,wglane+(size_t)2*6720 ,cgh+10,aq,ak,av,hsel,bsel);
    dd+=c0*dot_group<1>(aq,ak,sWd,nd,qp);
    #pragma unroll
    for(int r=0;r<4;++r) row[4*qp+r]=av[0][r];           // park unscaled
  }
  { // l3 = 1 : paths 3,4,5,6
    f32x4 aq[3]={z4,z4,z4}, ak[3]={z4,z4,z4}, av[3]={z4,z4,z4};
    do_path<1,3,3>(xrow,wglane+(size_t)3*6720 ,cgh+35,aq,ak,av,hsel,bsel);
    do_path<3,1,3>(xrow,wglane+(size_t)4*6720 ,cgh+44,aq,ak,av,hsel,bsel);
    do_path<3,5,3>(xrow,wglane+(size_t)5*6720 ,cgh+53,aq,ak,av,hsel,bsel);
    do_path<5,3,3>(xrow,wglane+(size_t)6*6720 ,cgh+98,aq,ak,av,hsel,bsel);
    dd+=c1*dot_group<3>(aq,ak,sWd+256,nd,qp);
    #pragma unroll
    for(int m=0;m<3;++m)
      #pragma unroll
      for(int r=0;r<4;++r) row[16+(4*qp+r)*3+m]=av[m][r];
  }
  { // l3 = 2 : paths 7,8,9,10
    f32x4 aq[5]={z4,z4,z4,z4,z4}, ak[5]={z4,z4,z4,z4,z4}, av[5]={z4,z4,z4,z4,z4};
    do_path<1,5,5>(xrow,wglane+(size_t)7*6720 ,cgh+143,aq,ak,av,hsel,bsel);
    do_path<3,3,5>(xrow,wglane+(size_t)8*6720 ,cgh+168,aq,ak,av,hsel,bsel);
    do_path<5,1,5>(xrow,wglane+(size_t)9*6720 ,cgh+213,aq,ak,av,hsel,bsel);
    do_path<5,5,5>(xrow,wglane+(size_t)10*6720,cgh+238,aq,ak,av,hsel,bsel);
    dd+=c2*dot_group<5>(aq,ak,sWd+512,nd,qp);
    #pragma unroll
    for(int m=0;m<5;++m)
      #pragma unroll
      for(int r=0;r<4;++r) row[64+(4*qp+r)*5+m]=av[m][r];
  }

  // ---- attention scalar (reduce over the node's 4 u-lanes) ----
  dd+=__shfl_xor(dd,16,64);
  dd+=__shfl_xor(dd,32,64);
  float ex=dd*0.03608439182435161f*(1.0f/12.0f);   // *sqrt(1/768) / sqrt(144)
  ex=fminf(fmaxf(ex,-80.f),80.f);
  float e=expf(ex);
  float attn=e/(e+1e-10f);
  if(qp==0) ((float*)SM)[ATOFF+nl]=attn;

  __syncthreads();          // all rows parked + attn published

  // ---- coalesced store: out = elu(attn[n] * v[n,f]) ----
  const float* img=(const float*)SM;
  const float* at=(const float*)SM+ATOFF;
  if(!xf32){
    unsigned int* ob=(unsigned int*)outp;
    for(int t=tid;t<64*72;t+=256){
      int n=t/72, fp=t-n*72;
      if(n<nvalid){
        float an=at[n];
        float v0=an*img[n*148+2*fp], v1=an*img[n*148+2*fp+1];
        v0=(v0>0.f)?v0:expm1f(v0);
        v1=(v1>0.f)?v1:expm1f(v1);
        ob[(size_t)(node0+n)*72+fp]=rne16(v0)|(rne16(v1)<<16);
      }
    }
  }else{
    float* outf=(float*)outp;
    for(int t=tid;t<64*144;t+=256){
      int n=t/144, f=t-n*144;
      if(n<nvalid){
        float v=at[n]*img[n*148+f];
        outf[(size_t)(node0+n)*144+f]=(v>0.f)?v:expm1f(v);
      }
    }
  }
}

extern "C" void kernel_launch(void* const* d_in, const int* in_sizes, int n_in,
                              void* d_out, int out_size, void* d_ws, size_t ws_size,
                              hipStream_t stream){
  (void)n_in; (void)out_size; (void)ws_size;
  const unsigned short* x =(const unsigned short*)d_in[0];
  const unsigned short* wq=(const unsigned short*)d_in[4];
  const unsigned short* wk=(const unsigned short*)d_in[5];
  const unsigned short* wv=(const unsigned short*)d_in[6];
  const unsigned short* wd=(const unsigned short*)d_in[7];
  float* c3j=(float*)d_ws;                                 // [0..362] w3j, [363..367] flags
  unsigned int* cgh=(unsigned int*)d_ws+1024;              // packed scale*C fp16 pairs (363)
  unsigned int* wpre=(unsigned int*)d_ws+2048;             // 11*3*2240 packed fp16 W^T
  int N=in_sizes[0]/144;
  prep<<<dim3(NP,3),dim3(256),0,stream>>>(x,wq,wk,wv,wd,
      in_sizes[0],in_sizes[4],in_sizes[7],c3j,cgh,wpre);
  int nb=(N+63)/64;
  tfn_main<<<dim3(nb),dim3(256),0,stream>>>(x,wpre,cgh,wd,c3j,(unsigned short*)d_out,N);
}